// Round 1
// baseline (11999.400 us; speedup 1.0000x reference)
//
#include <hip/hip_runtime.h>
#include <math.h>

// Problem constants (B=32, L=1024 -> M = 32768 rows)
#define MROWS  32768
#define HID    1024
#define INF    512

// Tile config: 128x64 C-tile, BK=16, 256 threads, per-thread 8x4 per matrix x 3 matrices
#define BM 128
#define BN 64
#define BK 16

typedef float f4 __attribute__((ext_vector_type(4)));

__device__ __forceinline__ float sigm(float x) { return 1.0f / (1.0f + expf(-x)); }

// Fused triple-GEMM + epilogue.
//   C_q[m][n] = sum_k A[m][k] * Wq[n][k]   (q = 0,1,2; W row-major [1024][K])
// IS_GRU epilogue:  r=sig(c0+b0+bh_r); z=sig(c1+b1+bh_z); n=tanh(c2+b2+r*bh_n); out=(1-z)*n
// step epilogue:    hh=tanh(c0+b0); t=sig(c1+b1); c=sig(c2+b2); out=hh*t + A[m][n]*(1-c)
template <int K, bool IS_GRU>
__global__ __launch_bounds__(256, 2) void rhn_gemm3(
    const float* __restrict__ A,
    const float* __restrict__ W0, const float* __restrict__ W1, const float* __restrict__ W2,
    const float* __restrict__ b0, const float* __restrict__ b1, const float* __restrict__ b2,
    const float* __restrict__ bhh,  // GRU only (3*HID), else unused
    float* __restrict__ out)
{
    __shared__ float As[BK][BM + 4];      // transposed A tile, +4 pad keeps 16B align
    __shared__ float Ws[3][BK][BN + 4];   // transposed W tiles

    const int tid = threadIdx.x;
    const int m0 = blockIdx.y * BM;
    const int n0 = blockIdx.x * BN;

    const int tm = tid & 15;        // 16 row-groups
    const int tn = tid >> 4;        // 16 col-groups
    const int lrow = tid >> 2;      // 0..63 (loader row)
    const int lcol = (tid & 3) * 4; // 0,4,8,12 (loader col, float4 granule)

    float acc[3][8][4];
#pragma unroll
    for (int q = 0; q < 3; q++)
#pragma unroll
        for (int i = 0; i < 8; i++)
#pragma unroll
            for (int j = 0; j < 4; j++) acc[q][i][j] = 0.0f;

    for (int k0 = 0; k0 < K; k0 += BK) {
        // ---- stage A tile (128x16) ----
#pragma unroll
        for (int p = 0; p < 2; p++) {
            const int row = p * 64 + lrow;
            f4 v = *(const f4*)&A[(size_t)(m0 + row) * K + k0 + lcol];
#pragma unroll
            for (int j = 0; j < 4; j++) As[lcol + j][row] = v[j];
        }
        // ---- stage 3 W tiles (64x16 each) ----
        {
            const size_t wo = (size_t)(n0 + lrow) * K + k0 + lcol;
            f4 v0 = *(const f4*)&W0[wo];
            f4 v1 = *(const f4*)&W1[wo];
            f4 v2 = *(const f4*)&W2[wo];
#pragma unroll
            for (int j = 0; j < 4; j++) {
                Ws[0][lcol + j][lrow] = v0[j];
                Ws[1][lcol + j][lrow] = v1[j];
                Ws[2][lcol + j][lrow] = v2[j];
            }
        }
        __syncthreads();

        // ---- compute ----
#pragma unroll
        for (int kk = 0; kk < BK; kk++) {
            f4 a0 = *(const f4*)&As[kk][tm * 4];
            f4 a1 = *(const f4*)&As[kk][64 + tm * 4];
            f4 w0 = *(const f4*)&Ws[0][kk][tn * 4];
            f4 w1 = *(const f4*)&Ws[1][kk][tn * 4];
            f4 w2 = *(const f4*)&Ws[2][kk][tn * 4];
#pragma unroll
            for (int i = 0; i < 4; i++) {
#pragma unroll
                for (int j = 0; j < 4; j++) {
                    acc[0][i][j]     += a0[i] * w0[j];
                    acc[0][i + 4][j] += a1[i] * w0[j];
                    acc[1][i][j]     += a0[i] * w1[j];
                    acc[1][i + 4][j] += a1[i] * w1[j];
                    acc[2][i][j]     += a0[i] * w2[j];
                    acc[2][i + 4][j] += a1[i] * w2[j];
                }
            }
        }
        __syncthreads();
    }

    // ---- epilogue ----
    const int col0 = n0 + tn * 4;
    f4 vb0 = *(const f4*)&b0[col0];
    f4 vb1 = *(const f4*)&b1[col0];
    f4 vb2 = *(const f4*)&b2[col0];
    f4 vh0, vh1, vh2;
    if constexpr (IS_GRU) {
        vh0 = *(const f4*)&bhh[col0];
        vh1 = *(const f4*)&bhh[HID + col0];
        vh2 = *(const f4*)&bhh[2 * HID + col0];
    }

#pragma unroll
    for (int i = 0; i < 8; i++) {
        const int row = m0 + tm * 4 + (i < 4 ? i : 60 + i);  // 4+4 split blocking
        f4 res;
        if constexpr (IS_GRU) {
#pragma unroll
            for (int j = 0; j < 4; j++) {
                float r = sigm(acc[0][i][j] + vb0[j] + vh0[j]);
                float z = sigm(acc[1][i][j] + vb1[j] + vh1[j]);
                float n = tanhf(acc[2][i][j] + vb2[j] + r * vh2[j]);
                res[j] = (1.0f - z) * n;
            }
        } else {
            f4 hold = *(const f4*)&A[(size_t)row * HID + col0];
#pragma unroll
            for (int j = 0; j < 4; j++) {
                float hh = tanhf(acc[0][i][j] + vb0[j]);
                float tt = sigm(acc[1][i][j] + vb1[j]);
                float cc = sigm(acc[2][i][j] + vb2[j]);
                res[j] = hh * tt + hold[j] * (1.0f - cc);
            }
        }
        *(f4*)&out[(size_t)row * HID + col0] = res;
    }
}

extern "C" void kernel_launch(void* const* d_in, const int* in_sizes, int n_in,
                              void* d_out, int out_size, void* d_ws, size_t ws_size,
                              hipStream_t stream) {
    const float* x    = (const float*)d_in[0];   // [32,1024,512]
    const float* w_ih = (const float*)d_in[1];   // [3072,512]
    // d_in[2] = w_hh: zero contribution (h0 = 0) -> unused
    const float* b_ih = (const float*)d_in[3];   // [3072]
    const float* b_hh = (const float*)d_in[4];   // [3072]
    const float* WH   = (const float*)d_in[5];   // [5,1024,1024]
    const float* bH   = (const float*)d_in[6];   // [5,1024]
    const float* WT   = (const float*)d_in[7];
    const float* bT   = (const float*)d_in[8];
    const float* WC   = (const float*)d_in[9];
    const float* bC   = (const float*)d_in[10];

    float* out = (float*)d_out;                  // [32768,1024]
    float* ws  = (float*)d_ws;                   // ping buffer (134 MB)

    dim3 grid(HID / BN, MROWS / BM);             // (16, 256)
    dim3 block(256);

    // GRU phase: x -> h0' into ws
    rhn_gemm3<INF, true><<<grid, block, 0, stream>>>(
        x, w_ih, w_ih + (size_t)HID * INF, w_ih + (size_t)2 * HID * INF,
        b_ih, b_ih + HID, b_ih + 2 * HID, b_hh, ws);

    // 5 highway micro-steps, ping-pong ws <-> out; step 4 lands in out.
    const float* src = ws;
    for (int s = 0; s < 5; s++) {
        float* dst = (s & 1) ? ws : out;
        rhn_gemm3<HID, false><<<grid, block, 0, stream>>>(
            src,
            WH + (size_t)s * HID * HID, WT + (size_t)s * HID * HID, WC + (size_t)s * HID * HID,
            bH + s * HID, bT + s * HID, bC + s * HID,
            nullptr, dst);
        src = dst;
    }
}

// Round 3
// 2130.640 us; speedup vs baseline: 5.6318x; 5.6318x over previous
//
#include <hip/hip_runtime.h>
#include <math.h>

#define MROWS 32768
#define MH    16384      // process M in two halves to fit ws
#define HID   1024
#define KGRU  512

typedef float          f32x4  __attribute__((ext_vector_type(4)));
typedef short          bf16x8 __attribute__((ext_vector_type(8)));
typedef unsigned short u16x4  __attribute__((ext_vector_type(4)));

__device__ __forceinline__ float sigm(float x) { return 1.0f / (1.0f + expf(-x)); }

__device__ __forceinline__ unsigned short f2bf(float f) {
    union { float f; unsigned u; } v; v.f = f;
    unsigned r = v.u + 0x7FFFu + ((v.u >> 16) & 1u);   // RNE
    return (unsigned short)(r >> 16);
}

__device__ __forceinline__ void gld16(const void* g, void* l) {
    __builtin_amdgcn_global_load_lds((const __attribute__((address_space(1))) void*)g,
                                     (__attribute__((address_space(3))) void*)l, 16, 0, 0);
}

// Fused triple-GEMM, bf16 MFMA. C_q[m][n] = sum_k A[m][k] * Wq[n][k].
// Wq = W0 + q*HID*K (q-slices contiguous). Operands SWAPPED in mfma (W first),
// so per-lane D covers 4 consecutive n at fixed m -> vectorized epilogue.
template <int K, bool IS_GRU>
__global__ __launch_bounds__(256, 2) void gemm3(
    const unsigned short* __restrict__ Abf,   // [MH][K] bf16
    const unsigned short* __restrict__ W0,    // [3][HID][K] bf16
    const float* __restrict__ b0, const float* __restrict__ b1, const float* __restrict__ b2,
    const float* __restrict__ bhh,            // GRU only
    float* __restrict__ outF,                 // [MH][HID] fp32, in-place residual
    unsigned short* __restrict__ outBf)       // [MH][HID] bf16 (next step's A)
{
    __shared__ short Al[16 * 512];   // 16 chunks x 1KB, fragment-packed
    __shared__ short Wl[24 * 512];   // 24 chunks x 1KB (3 mats x 8)

    const int tid  = threadIdx.x;
    const int lane = tid & 63;
    const int wid  = tid >> 6;
    const int wm   = wid >> 1;       // wave m half (0,1)
    const int wn   = wid & 1;        // wave n half (0,1)
    const int l15  = lane & 15;
    const int l4   = lane >> 4;

    // XCD-aware bijective swizzle (nwg = 2048, divisible by 8)
    const int nwg   = gridDim.x;
    const int cpx   = nwg >> 3;
    const int wg    = blockIdx.x;
    const int swz   = (wg & 7) * cpx + (wg >> 3);
    const int m0    = (swz >> 4) * 128;   // n-tiles fastest -> m-panel reuse per XCD
    const int n0    = (swz & 15) * 64;

    // staging source offsets (elements), fragment-packed mapping
    long aoff[4];
#pragma unroll
    for (int i = 0; i < 4; i++) {
        const int ca = wid * 4 + i;            // chunk = f*2 + ks
        const int f = ca >> 1, ks = ca & 1;
        aoff[i] = (long)(m0 + f * 16 + l15) * K + ks * 32 + l4 * 8;
    }
    long woff[6];
#pragma unroll
    for (int i = 0; i < 6; i++) {
        const int cw = wid * 6 + i;            // chunk = q*8 + nf*2 + ks
        const int q = cw >> 3, nf = (cw >> 1) & 3, ks = cw & 1;
        woff[i] = (long)q * HID * K + (long)(n0 + nf * 16 + l15) * K + ks * 32 + l4 * 8;
    }

    f32x4 acc[3][2][4];
#pragma unroll
    for (int q = 0; q < 3; q++)
#pragma unroll
        for (int c = 0; c < 2; c++)
#pragma unroll
            for (int f = 0; f < 4; f++) acc[q][c][f] = (f32x4)0.0f;

    for (int k0 = 0; k0 < K; k0 += 64) {
#pragma unroll
        for (int i = 0; i < 4; i++) gld16(Abf + aoff[i] + k0, Al + (wid * 4 + i) * 512);
#pragma unroll
        for (int i = 0; i < 6; i++) gld16(W0 + woff[i] + k0, Wl + (wid * 6 + i) * 512);
        __syncthreads();   // compiler drains vmcnt before barrier

#pragma unroll
        for (int ks = 0; ks < 2; ks++) {
            bf16x8 ha[4], wb[3][2];
#pragma unroll
            for (int f = 0; f < 4; f++)
                ha[f] = *(const bf16x8*)&Al[((wm * 4 + f) * 2 + ks) * 512 + lane * 8];
#pragma unroll
            for (int q = 0; q < 3; q++)
#pragma unroll
                for (int c = 0; c < 2; c++)
                    wb[q][c] = *(const bf16x8*)&Wl[(q * 8 + (wn * 2 + c) * 2 + ks) * 512 + lane * 8];
#pragma unroll
            for (int q = 0; q < 3; q++)
#pragma unroll
                for (int c = 0; c < 2; c++)
#pragma unroll
                    for (int f = 0; f < 4; f++)
                        acc[q][c][f] = __builtin_amdgcn_mfma_f32_16x16x32_bf16(
                            wb[q][c], ha[f], acc[q][c][f], 0, 0, 0);
        }
        __syncthreads();
    }

    // ---- epilogue: lane holds (m = m0+wm*64+f*16+l15, n = gn + r), r=0..3 ----
    const int gn0 = n0 + wn * 32 + l4 * 4;
    const int gn1 = gn0 + 16;
    f32x4 vb[3][2], vh[3][2];
    vb[0][0] = *(const f32x4*)&b0[gn0]; vb[0][1] = *(const f32x4*)&b0[gn1];
    vb[1][0] = *(const f32x4*)&b1[gn0]; vb[1][1] = *(const f32x4*)&b1[gn1];
    vb[2][0] = *(const f32x4*)&b2[gn0]; vb[2][1] = *(const f32x4*)&b2[gn1];
    if constexpr (IS_GRU) {
        vh[0][0] = *(const f32x4*)&bhh[gn0];           vh[0][1] = *(const f32x4*)&bhh[gn1];
        vh[1][0] = *(const f32x4*)&bhh[HID + gn0];     vh[1][1] = *(const f32x4*)&bhh[HID + gn1];
        vh[2][0] = *(const f32x4*)&bhh[2 * HID + gn0]; vh[2][1] = *(const f32x4*)&bhh[2 * HID + gn1];
    }

#pragma unroll
    for (int f = 0; f < 4; f++) {
        const long gm = m0 + wm * 64 + f * 16 + l15;
#pragma unroll
        for (int c = 0; c < 2; c++) {
            const int gn = c ? gn1 : gn0;
            const f32x4 g0 = acc[0][c][f], g1 = acc[1][c][f], g2 = acc[2][c][f];
            f32x4 res;
            if constexpr (IS_GRU) {
#pragma unroll
                for (int j = 0; j < 4; j++) {
                    float r = sigm(g0[j] + vb[0][c][j] + vh[0][c][j]);
                    float z = sigm(g1[j] + vb[1][c][j] + vh[1][c][j]);
                    float n = tanhf(g2[j] + vb[2][c][j] + r * vh[2][c][j]);
                    res[j] = (1.0f - z) * n;
                }
            } else {
                const f32x4 hold = *(const f32x4*)&outF[gm * HID + gn];
#pragma unroll
                for (int j = 0; j < 4; j++) {
                    float hh = tanhf(g0[j] + vb[0][c][j]);
                    float tt = sigm(g1[j] + vb[1][c][j]);
                    float cc = sigm(g2[j] + vb[2][c][j]);
                    res[j] = hh * tt + hold[j] * (1.0f - cc);
                }
            }
            *(f32x4*)&outF[gm * HID + gn] = res;
            u16x4 rb;
#pragma unroll
            for (int j = 0; j < 4; j++) rb[j] = f2bf(res[j]);
            *(u16x4*)&outBf[gm * HID + gn] = rb;
        }
    }
}

// fp32 -> bf16, plain
__global__ void convP(const float* __restrict__ s, unsigned short* __restrict__ d, int n) {
    int i = (blockIdx.x * blockDim.x + threadIdx.x) * 4;
    const int stride = gridDim.x * blockDim.x * 4;
    for (; i < n; i += stride) {
        f32x4 v = *(const f32x4*)&s[i];
        u16x4 r;
#pragma unroll
        for (int j = 0; j < 4; j++) r[j] = f2bf(v[j]);
        *(u16x4*)&d[i] = r;
    }
}

// fp32 -> bf16, scatter 5 chunks of HID*HID into stride 3*HID*HID (interleave WH/WT/WC)
__global__ void convS(const float* __restrict__ s, unsigned short* __restrict__ d, int n) {
    int i = (blockIdx.x * blockDim.x + threadIdx.x) * 4;
    const int stride = gridDim.x * blockDim.x * 4;
    for (; i < n; i += stride) {
        f32x4 v = *(const f32x4*)&s[i];
        u16x4 r;
#pragma unroll
        for (int j = 0; j < 4; j++) r[j] = f2bf(v[j]);
        const int di = (i >> 20) * (3 * HID * HID) + (i & (HID * HID - 1));
        *(u16x4*)&d[di] = r;
    }
}

extern "C" void kernel_launch(void* const* d_in, const int* in_sizes, int n_in,
                              void* d_out, int out_size, void* d_ws, size_t ws_size,
                              hipStream_t stream) {
    const float* x    = (const float*)d_in[0];
    const float* w_ih = (const float*)d_in[1];
    const float* b_ih = (const float*)d_in[3];
    const float* b_hh = (const float*)d_in[4];
    const float* WH   = (const float*)d_in[5];
    const float* bH   = (const float*)d_in[6];
    const float* WT   = (const float*)d_in[7];
    const float* bT   = (const float*)d_in[8];
    const float* WC   = (const float*)d_in[9];
    const float* bC   = (const float*)d_in[10];

    float* out = (float*)d_out;               // [32768][1024] fp32, in-place h
    char*  ws  = (char*)d_ws;

    // ws layout (bytes): wih_bf 3.1MB | W_bf 31.5MB | ping 33.6MB | pong 33.6MB  (=101.7MB)
    unsigned short* wih_bf = (unsigned short*)ws;
    unsigned short* W_bf   = (unsigned short*)(ws + (size_t)3 * HID * KGRU * 2);
    const size_t off_ping  = (size_t)3 * HID * KGRU * 2 + (size_t)15 * HID * HID * 2;
    unsigned short* ping   = (unsigned short*)(ws + off_ping);
    unsigned short* pong   = (unsigned short*)(ws + off_ping + (size_t)MH * HID * 2);
    // x_bf aliases pong (dead after GRU reads it; step0 then overwrites)

    dim3 blk(256);

    // weight conversions (every call; ws is re-poisoned)
    convP<<<1024, blk, 0, stream>>>(w_ih, wih_bf, 3 * HID * KGRU);
    convS<<<2048, blk, 0, stream>>>(WH, W_bf + 0 * HID * HID, 5 * HID * HID);
    convS<<<2048, blk, 0, stream>>>(WT, W_bf + 1 * HID * HID, 5 * HID * HID);
    convS<<<2048, blk, 0, stream>>>(WC, W_bf + 2 * HID * HID, 5 * HID * HID);

    for (int h = 0; h < 2; h++) {
        const float* xh   = x + (size_t)h * MH * KGRU;
        float*       outh = out + (size_t)h * MH * HID;

        convP<<<2048, blk, 0, stream>>>(xh, pong, MH * KGRU);

        // GRU: A = x_bf(pong), writes fp32 h -> outh, bf16 h -> ping
        gemm3<KGRU, true><<<2048, blk, 0, stream>>>(
            pong, wih_bf, b_ih, b_ih + HID, b_ih + 2 * HID, b_hh, outh, ping);

        // 5 highway steps: bf16 A ping-pongs; fp32 h in-place in outh
        const unsigned short* src = ping;
        for (int s = 0; s < 5; s++) {
            unsigned short* dst = (s & 1) ? ping : pong;
            gemm3<HID, false><<<2048, blk, 0, stream>>>(
                src, W_bf + (size_t)s * 3 * HID * HID,
                bH + s * HID, bT + s * HID, bC + s * HID, nullptr, outh, dst);
            src = dst;
        }
    }
}